// Round 3
// baseline (414.606 us; speedup 1.0000x reference)
//
#include <hip/hip_runtime.h>
#include <math.h>

#define LAM 0.3f
#define EPS 1e-8f

constexpr int B = 32, T = 12, N = 5000, C = 8, E = 5000, M = 160000;
constexpr int F = 16;          // 2*C feature dim
constexpr int RH = B * F;      // 512 halves per node across ALL batches
constexpr int HR = 256;        // halves per node per batch-half (16 b x 16 f)
constexpr size_t HN = (size_t)N * HR; // halves per batch-half region
constexpr int SIM_GRID = 2512; // sim kernel grid (padded; 314 groups of 8)

typedef _Float16 half8 __attribute__((ext_vector_type(8)));
typedef _Float16 half2v __attribute__((ext_vector_type(2)));

__device__ __forceinline__ float dot16(const half8& m, const half8& c, float p0) {
    float p = p0;
#if __has_builtin(__builtin_amdgcn_fdot2)
#pragma unroll
    for (int k = 0; k < 4; ++k) {
        half2v a = {m[2 * k], m[2 * k + 1]};
        half2v c2 = {c[2 * k], c[2 * k + 1]};
        p = __builtin_amdgcn_fdot2(a, c2, p, false);
    }
#else
#pragma unroll
    for (int k = 0; k < 8; ++k) p = fmaf((float)m[k], (float)c[k], p);
#endif
    return p;
}

__device__ __forceinline__ float clip01(float p) {
    return fminf(fmaxf(p, 0.0f), 1.0f);
}

// ---------------------------------------------------------------------------
// Kernel 1 (fused): blocks 0..624 -> 8 nodes x 32 batches (one (b,n)/thread).
// mean/std over T, unit-normalize, fp16, transpose via padded LDS, write out
// as ufeat[h][n][256] (h = b>>4): 2 x 4KB contiguous coalesced sweeps/block.
// Block 625 -> exclusive prefix scan of counts -> starts, and zeroes the
// ticket counter used by the fused sim+norm kernel.
// ---------------------------------------------------------------------------
__global__ __launch_bounds__(256) void feat_scan_kernel(const float* __restrict__ x,
                                                        const float* __restrict__ counts,
                                                        _Float16* __restrict__ ufeat,
                                                        int* __restrict__ starts,
                                                        int* __restrict__ cbar) {
    if (blockIdx.x == 625) {
        constexpr int PER = (E + 255) / 256; // 20
        __shared__ int tsum[256];
        int tid = threadIdx.x;
        if (tid == 0) cbar[0] = 0;           // reset ticket counter every launch
        int base = tid * PER;
        int local[PER];
        int s = 0;
#pragma unroll
        for (int k = 0; k < PER; ++k) {
            int e = base + k;
            int c = (e < E) ? (int)counts[e] : 0;
            local[k] = s;
            s += c;
        }
        tsum[tid] = s;
        __syncthreads();
        for (int off = 1; off < 256; off <<= 1) {
            int v = (tid >= off) ? tsum[tid - off] : 0;
            __syncthreads();
            tsum[tid] += v;
            __syncthreads();
        }
        int prefix = (tid == 0) ? 0 : tsum[tid - 1];
#pragma unroll
        for (int k = 0; k < PER; ++k) {
            int e = base + k;
            if (e < E) starts[e] = prefix + local[k];
        }
        return;
    }

    // ---- feat: 625 blocks x (8 nodes, 32 batches) ----
    int tid = threadIdx.x;
    int nb = blockIdx.x * 8;   // node base (625*8 = 5000 exact)
    int nl = tid & 7;          // node local
    int b  = tid >> 3;         // batch 0..31
    int n  = nb + nl;

    const float* p = x + ((size_t)b * T * N + n) * C;

    float s[8] = {0, 0, 0, 0, 0, 0, 0, 0};
    float q2[8] = {0, 0, 0, 0, 0, 0, 0, 0};
#pragma unroll
    for (int t = 0; t < T; ++t) {
        const float* pt = p + (size_t)t * N * C;
        float4 a = *(const float4*)(pt);
        float4 bq = *(const float4*)(pt + 4);
        float v[8] = {a.x, a.y, a.z, a.w, bq.x, bq.y, bq.z, bq.w};
#pragma unroll
        for (int c = 0; c < 8; ++c) {
            s[c] += v[c];
            q2[c] += v[c] * v[c];
        }
    }

    float u[16];
    float n2 = 0.0f;
#pragma unroll
    for (int c = 0; c < 8; ++c) {
        float mean = s[c] * (1.0f / T);
        float var = (q2[c] - s[c] * mean) * (1.0f / (T - 1));
        float sd = sqrtf(fmaxf(var, 0.0f));
        u[c] = mean;
        u[8 + c] = sd;
        n2 += mean * mean + sd * sd;
    }
    float scale = 1.0f / fmaxf(sqrtf(n2), EPS);

    // LDS transpose: sfeat[node][b*16+f], row padded +8 halves
    __shared__ _Float16 sfeat[8][RH + 8];
    half8 h0, h1;
#pragma unroll
    for (int c = 0; c < 8; ++c) h0[c] = (_Float16)(u[c] * scale);
#pragma unroll
    for (int c = 0; c < 8; ++c) h1[c] = (_Float16)(u[8 + c] * scale);
    *(half8*)&sfeat[nl][b * F + 0] = h0;
    *(half8*)&sfeat[nl][b * F + 8] = h1;
    __syncthreads();

    // coalesced write-out into [h][n][256]: per h, 8 rows x 512B = 4KB contiguous
#pragma unroll
    for (int h = 0; h < 2; ++h) {
        int nr = tid >> 5;           // row 0..7
        int off = tid & 31;          // 16B granule within 512B row
        half8 v = *(const half8*)&sfeat[nr][(h * 16 + (off >> 1)) * F + (off & 1) * 8];
        *(half8*)(ufeat + (size_t)h * HN + (size_t)(nb + nr) * HR + off * 8) = v;
    }
}

// ---------------------------------------------------------------------------
// Kernel 2 (fused sim + norm): one wave per (edge, batch-half).  Block swizzle
// maps batch-half h to XCD group so each XCD's L2 serves one 2.56MB half.
// Sim core is byte-identical to the passing R1 version (SGPR member indices,
// wave-uniform bounds -- per-half-wave divergent bounds fail on HW, R6/R7).
// Ticket fusion of K3.  R9 FAILED (absmax 0.226) because thread 0 drew the
// block's ticket BEFORE other waves finished their mean_sim stores:
// __threadfence is per-thread; there was no __syncthreads between stores and
// the ticket RMW.  Fixed sequence (the cooperative-groups grid-barrier
// pattern): store -> __threadfence (each thread) -> __syncthreads -> thread-0
// release RMW.  Spin side: thread-0 acquire -> __syncthreads -> per-thread
// __threadfence -> reads.  Deadlock-free: a block spins only after drawing
// its own ticket; <=32 spinners cannot starve the remaining blocks.
// ---------------------------------------------------------------------------
__global__ __launch_bounds__(256) void sim_norm_kernel(const _Float16* __restrict__ ufeat,
                                                       const int* __restrict__ members,
                                                       const int* __restrict__ centers,
                                                       const int* __restrict__ starts,
                                                       const float* __restrict__ counts,
                                                       float* __restrict__ mean_sim,
                                                       const float* __restrict__ W,
                                                       float* __restrict__ out,
                                                       int* __restrict__ cbar) {
    int linear = blockIdx.x;                     // 0..2511 (padded)
    int h = (linear & 4) >> 2;                   // XCDs 0-3 -> h=0, 4-7 -> h=1
    int e4 = (linear >> 3) * 4 + (linear & 3);   // edge-quad 0..1255 (padded)

    if (e4 < E / 4) {
        int wid = __builtin_amdgcn_readfirstlane(threadIdx.x >> 6); // wave id, SGPR
        int e = e4 * 4 + wid;                    // uniform
        int lane = threadIdx.x & 63;
        int g32 = lane & 31;   // 16B granule within 512B row
        int hw = lane >> 5;    // half-wave id -> member parity

        int start = __builtin_amdgcn_readfirstlane(starts[e]);
        int cnt   = __builtin_amdgcn_readfirstlane((int)counts[e]);
        int ce    = __builtin_amdgcn_readfirstlane(centers[e]);
        float cntf = (float)cnt;

        const _Float16* base = ufeat + (size_t)h * HN;
        const half8 c8 = *(const half8*)(base + (size_t)ce * HR + g32 * 8);
        const char* cbase = (const char*)base + (size_t)g32 * 16; // per-lane base

        float acc = 0.0f;
        const int* sp = members + start;         // wave-uniform pointer

        int nfull = cnt >> 4;
        for (int cc = 0; cc < nfull; ++cc) {
            int sm[16];
#pragma unroll
            for (int k = 0; k < 16; ++k)
                sm[k] = __builtin_amdgcn_readfirstlane(sp[k]);   // -> s_load
            sp += 16;
#pragma unroll
            for (int k = 0; k < 8; ++k) {
                int offA = sm[2 * k] * 512;      // scalar shifts
                int offB = sm[2 * k + 1] * 512;
                int off = hw ? offB : offA;      // one cndmask
                half8 a = *(const half8*)(cbase + off);
                float p = dot16(a, c8, 0.0f);
                p += __shfl_xor(p, 1);           // quad-perm DPP
                acc += clip01(p);
            }
        }

        int rem = cnt & 15;
        if (rem) {
            int sm[16];
#pragma unroll
            for (int k = 0; k < 16; ++k) {
                int idx = (k < rem) ? k : (rem - 1); // clamp: never OOB
                sm[k] = __builtin_amdgcn_readfirstlane(sp[idx]);
            }
#pragma unroll
            for (int k = 0; k < 8; ++k) {
                int j0 = 2 * k, j1 = 2 * k + 1;
                if (j0 < rem) {                  // uniform scalar guard
                    bool pair = (j1 < rem);
                    int offA = sm[j0] * 512;
                    int offB = (pair ? sm[j1] : sm[j0]) * 512;
                    int off = hw ? offB : offA;
                    half8 a = *(const half8*)(cbase + off);
                    float p = dot16(a, c8, 0.0f);
                    p += __shfl_xor(p, 1);
                    float v = clip01(p);
                    acc += (pair || hw == 0) ? v : 0.0f; // odd member counted once
                }
            }
        }

        acc += __shfl_xor(acc, 32);      // combine the two member-parity halves
        if (lane < 32 && (g32 & 1) == 0) {
            int b = h * 16 + (g32 >> 1);
            mean_sim[(size_t)b * E + e] = acc / fmaxf(cntf, 1.0f);
        }
    }

    // ---- ticket: publish stores (fence), BARRIER, then draw ----
    __threadfence();                     // each thread flushes its own stores
    __syncthreads();                     // ALL waves of this block have fenced
    __shared__ int ticket_s;
    if (threadIdx.x == 0) {
        ticket_s = __hip_atomic_fetch_add(cbar, 1, __ATOMIC_ACQ_REL,
                                          __HIP_MEMORY_SCOPE_AGENT);
    }
    __syncthreads();
    int ticket = ticket_s;
    if (ticket < SIM_GRID - B) return;   // non-norm blocks retire

    // ---- norm phase: last 32 tickets, one batch each ----
    if (threadIdx.x == 0) {
        while (__hip_atomic_load(cbar, __ATOMIC_ACQUIRE,
                                 __HIP_MEMORY_SCOPE_AGENT) < SIM_GRID) {
            __builtin_amdgcn_s_sleep(2);
        }
    }
    __syncthreads();
    __threadfence();                     // acquire: invalidate, see all blocks

    int b = ticket - (SIM_GRID - B);
    const float* row = mean_sim + (size_t)b * E;
    float mn = INFINITY, mx = -INFINITY;
    for (int e = threadIdx.x; e < E; e += 256) {
        float v = row[e];
        mn = fminf(mn, v);
        mx = fmaxf(mx, v);
    }
#pragma unroll
    for (int off = 32; off > 0; off >>= 1) {
        mn = fminf(mn, __shfl_xor(mn, off));
        mx = fmaxf(mx, __shfl_xor(mx, off));
    }
    __shared__ float smn[4], smx[4];
    int w = threadIdx.x >> 6, lane = threadIdx.x & 63;
    if (lane == 0) { smn[w] = mn; smx[w] = mx; }
    __syncthreads();
    float mnv = fminf(fminf(smn[0], smn[1]), fminf(smn[2], smn[3]));
    float mxv = fmaxf(fmaxf(smx[0], smx[1]), fmaxf(smx[2], smx[3]));
    float inv = 1.0f / (mxv - mnv + EPS);
    for (int e = threadIdx.x; e < E; e += 256) {
        out[(size_t)b * E + e] = W[e] * (1.0f + LAM * (row[e] - mnv) * inv);
    }
}

extern "C" void kernel_launch(void* const* d_in, const int* in_sizes, int n_in,
                              void* d_out, int out_size, void* d_ws, size_t ws_size,
                              hipStream_t stream) {
    const float* x_raw    = (const float*)d_in[0];
    const float* W        = (const float*)d_in[1];
    const int*   members  = (const int*)d_in[2];
    const int*   centers  = (const int*)d_in[3];
    const int*   edge_ids = (const int*)d_in[4]; (void)edge_ids;
    const float* counts   = (const float*)d_in[5];
    float* out = (float*)d_out;

    _Float16* ufeat   = (_Float16*)d_ws;                    // 2*N*256 halves = 5.12 MB
    float* mean_sim   = (float*)(ufeat + 2 * HN);           // B*E floats = 640 KB
    int*   starts     = (int*)(mean_sim + (size_t)B * E);   // E ints
    int*   cbar       = starts + E;                         // ticket counter

    feat_scan_kernel<<<626, 256, 0, stream>>>(x_raw, counts, ufeat, starts, cbar);
    // 2512 = 314 groups of 8 blocks (4 x h=0, 4 x h=1); e4 padded, checked in-kernel
    sim_norm_kernel<<<SIM_GRID, 256, 0, stream>>>(ufeat, members, centers, starts,
                                                  counts, mean_sim, W, out, cbar);
}

// Round 4
// 117.939 us; speedup vs baseline: 3.5154x; 3.5154x over previous
//
#include <hip/hip_runtime.h>
#include <math.h>

#define LAM 0.3f
#define EPS 1e-8f

constexpr int B = 32, T = 12, N = 5000, C = 8, E = 5000, M = 160000;
constexpr int F = 16;          // 2*C feature dim
constexpr int RH = B * F;      // 512 halves per node across ALL batches
constexpr int HR = 256;        // halves per node per batch-half (16 b x 16 f)
constexpr size_t HN = (size_t)N * HR; // halves per batch-half region

typedef _Float16 half8 __attribute__((ext_vector_type(8)));
typedef _Float16 half2v __attribute__((ext_vector_type(2)));

__device__ __forceinline__ float dot16(const half8& m, const half8& c, float p0) {
    float p = p0;
#if __has_builtin(__builtin_amdgcn_fdot2)
#pragma unroll
    for (int k = 0; k < 4; ++k) {
        half2v a = {m[2 * k], m[2 * k + 1]};
        half2v c2 = {c[2 * k], c[2 * k + 1]};
        p = __builtin_amdgcn_fdot2(a, c2, p, false);
    }
#else
#pragma unroll
    for (int k = 0; k < 8; ++k) p = fmaf((float)m[k], (float)c[k], p);
#endif
    return p;
}

__device__ __forceinline__ float clip01(float p) {
    return fminf(fmaxf(p, 0.0f), 1.0f);
}

// ---------------------------------------------------------------------------
// Kernel 1 (fused): blocks 0..624 -> 8 nodes x 32 batches (one (b,n)/thread).
// mean/std over T, unit-normalize, fp16, transpose via padded LDS, write out
// as ufeat[h][n][256] (h = b>>4): 2 x 4KB contiguous coalesced sweeps/block.
// Block 625 -> exclusive prefix scan of counts -> starts.
// At its HBM roofline: reads 61.4 MB of x_raw (~11 us at 6.3 TB/s).
// ---------------------------------------------------------------------------
__global__ __launch_bounds__(256) void feat_scan_kernel(const float* __restrict__ x,
                                                        const float* __restrict__ counts,
                                                        _Float16* __restrict__ ufeat,
                                                        int* __restrict__ starts) {
    if (blockIdx.x == 625) {
        constexpr int PER = (E + 255) / 256; // 20
        __shared__ int tsum[256];
        int tid = threadIdx.x;
        int base = tid * PER;
        int local[PER];
        int s = 0;
#pragma unroll
        for (int k = 0; k < PER; ++k) {
            int e = base + k;
            int c = (e < E) ? (int)counts[e] : 0;
            local[k] = s;
            s += c;
        }
        tsum[tid] = s;
        __syncthreads();
        for (int off = 1; off < 256; off <<= 1) {
            int v = (tid >= off) ? tsum[tid - off] : 0;
            __syncthreads();
            tsum[tid] += v;
            __syncthreads();
        }
        int prefix = (tid == 0) ? 0 : tsum[tid - 1];
#pragma unroll
        for (int k = 0; k < PER; ++k) {
            int e = base + k;
            if (e < E) starts[e] = prefix + local[k];
        }
        return;
    }

    // ---- feat: 625 blocks x (8 nodes, 32 batches) ----
    int tid = threadIdx.x;
    int nb = blockIdx.x * 8;   // node base (625*8 = 5000 exact)
    int nl = tid & 7;          // node local
    int b  = tid >> 3;         // batch 0..31
    int n  = nb + nl;

    const float* p = x + ((size_t)b * T * N + n) * C;

    float s[8] = {0, 0, 0, 0, 0, 0, 0, 0};
    float q2[8] = {0, 0, 0, 0, 0, 0, 0, 0};
#pragma unroll
    for (int t = 0; t < T; ++t) {
        const float* pt = p + (size_t)t * N * C;
        float4 a = *(const float4*)(pt);
        float4 bq = *(const float4*)(pt + 4);
        float v[8] = {a.x, a.y, a.z, a.w, bq.x, bq.y, bq.z, bq.w};
#pragma unroll
        for (int c = 0; c < 8; ++c) {
            s[c] += v[c];
            q2[c] += v[c] * v[c];
        }
    }

    float u[16];
    float n2 = 0.0f;
#pragma unroll
    for (int c = 0; c < 8; ++c) {
        float mean = s[c] * (1.0f / T);
        float var = (q2[c] - s[c] * mean) * (1.0f / (T - 1));
        float sd = sqrtf(fmaxf(var, 0.0f));
        u[c] = mean;
        u[8 + c] = sd;
        n2 += mean * mean + sd * sd;
    }
    float scale = 1.0f / fmaxf(sqrtf(n2), EPS);

    // LDS transpose: sfeat[node][b*16+f], row padded +8 halves
    __shared__ _Float16 sfeat[8][RH + 8];
    half8 h0, h1;
#pragma unroll
    for (int c = 0; c < 8; ++c) h0[c] = (_Float16)(u[c] * scale);
#pragma unroll
    for (int c = 0; c < 8; ++c) h1[c] = (_Float16)(u[8 + c] * scale);
    *(half8*)&sfeat[nl][b * F + 0] = h0;
    *(half8*)&sfeat[nl][b * F + 8] = h1;
    __syncthreads();

    // coalesced write-out into [h][n][256]: per h, 8 rows x 512B = 4KB contiguous
#pragma unroll
    for (int h = 0; h < 2; ++h) {
        int nr = tid >> 5;           // row 0..7
        int off = tid & 31;          // 16B granule within 512B row
        half8 v = *(const half8*)&sfeat[nr][(h * 16 + (off >> 1)) * F + (off & 1) * 8];
        *(half8*)(ufeat + (size_t)h * HN + (size_t)(nb + nr) * HR + off * 8) = v;
    }
}

// ---------------------------------------------------------------------------
// Kernel 2: one wave per (edge, batch-half).  Block swizzle maps batch-half h
// to XCD group so each XCD's L2 serves one 2.56MB half.
// Main loop: 8 members/iter with WAVE-UNIFORM bounds (jmax8 = chunk & ~7) ->
// 4 member-row loads in flight per half-wave; predicated pair-tail identical
// to R5.  NOTE: per-half-wave divergent loop bounds (R6/R7's nh-loop) fail
// reproducibly on HW (absmax 3.1e-2) -- keep ALL loop bounds wave-uniform.
// At its L2-gather latency floor: scalar-index variant (R8) measured
// identical; grid-ticket fusion of norm (R9/R10) was correct but +300 us --
// a single agent-scope acq-rel counter serializes ~130ns/block across XCDs.
// Norm stays a separate kernel.
// ---------------------------------------------------------------------------
__global__ __launch_bounds__(256) void sim_kernel(const _Float16* __restrict__ ufeat,
                                                  const int* __restrict__ members,
                                                  const int* __restrict__ centers,
                                                  const int* __restrict__ starts,
                                                  const float* __restrict__ counts,
                                                  float* __restrict__ mean_sim) {
    int linear = blockIdx.x;                     // 0..2511 (padded)
    int h = (linear & 4) >> 2;                   // XCDs 0-3 -> h=0, 4-7 -> h=1
    int e4 = (linear >> 3) * 4 + (linear & 3);   // edge-quad 0..1255 (padded)
    if (e4 >= E / 4) return;
    int e = e4 * 4 + (threadIdx.x >> 6);
    int lane = threadIdx.x & 63;
    int g32 = lane & 31;   // 16B granule within 512B row
    int hw = lane >> 5;    // half-wave id -> member parity

    int start = starts[e];
    float cntf = counts[e];
    int cnt = (int)cntf;
    int ce = centers[e];

    const _Float16* base = ufeat + (size_t)h * HN;
    const half8 c8 = *(const half8*)(base + (size_t)ce * HR + g32 * 8);

    float acc = 0.0f;
    for (int cb = 0; cb < cnt; cb += 64) {
        int chunk = min(64, cnt - cb);
        int myidx = (lane < chunk) ? members[start + cb + lane] : 0;
        int jmax8 = chunk & ~7;              // wave-uniform
        int j = 0;
        for (; j < jmax8; j += 8) {          // 4 loads in flight per half-wave
            int m0 = __shfl(myidx, j + 0 + hw);
            int m1 = __shfl(myidx, j + 2 + hw);
            int m2 = __shfl(myidx, j + 4 + hw);
            int m3 = __shfl(myidx, j + 6 + hw);
            half8 a0 = *(const half8*)(base + (size_t)m0 * HR + g32 * 8);
            half8 a1 = *(const half8*)(base + (size_t)m1 * HR + g32 * 8);
            half8 a2 = *(const half8*)(base + (size_t)m2 * HR + g32 * 8);
            half8 a3 = *(const half8*)(base + (size_t)m3 * HR + g32 * 8);
            float p0 = dot16(a0, c8, 0.0f);
            float p1 = dot16(a1, c8, 0.0f);
            float p2 = dot16(a2, c8, 0.0f);
            float p3 = dot16(a3, c8, 0.0f);
            p0 += __shfl_xor(p0, 1);
            p1 += __shfl_xor(p1, 1);
            p2 += __shfl_xor(p2, 1);
            p3 += __shfl_xor(p3, 1);
            acc += clip01(p0) + clip01(p1) + clip01(p2) + clip01(p3);
        }
        for (; j < chunk; j += 2) {          // predicated pair-tail (R5-exact)
            int jj = j + hw;
            int mi = __shfl(myidx, (jj < chunk) ? jj : j);
            half8 m8 = *(const half8*)(base + (size_t)mi * HR + g32 * 8);
            float p = dot16(m8, c8, 0.0f);
            p += __shfl_xor(p, 1);
            float v = clip01(p);
            acc += (jj < chunk) ? v : 0.0f;
        }
    }
    acc += __shfl_xor(acc, 32);      // combine the two member-parity halves
    if (lane < 32 && (g32 & 1) == 0) {
        int b = h * 16 + (g32 >> 1);
        mean_sim[(size_t)b * E + e] = acc / fmaxf(cntf, 1.0f);
    }
}

// ---------------------------------------------------------------------------
// Kernel 3: per-batch min/max over E then write W[e]*(1+LAM*norm).
// One 1024-thread block per b.  Kept as a separate launch: fusing via a
// grid ticket costs ~300 us (XCD-serialized atomic); a launch gap is ~5 us.
// ---------------------------------------------------------------------------
__global__ __launch_bounds__(1024) void norm_kernel(const float* __restrict__ mean_sim,
                                                    const float* __restrict__ W,
                                                    float* __restrict__ out) {
    int b = blockIdx.x;
    const float* row = mean_sim + (size_t)b * E;
    float mn = INFINITY, mx = -INFINITY;
    for (int e = threadIdx.x; e < E; e += 1024) {
        float v = row[e];
        mn = fminf(mn, v);
        mx = fmaxf(mx, v);
    }
#pragma unroll
    for (int off = 32; off > 0; off >>= 1) {
        mn = fminf(mn, __shfl_down(mn, off));
        mx = fmaxf(mx, __shfl_down(mx, off));
    }
    __shared__ float smn[16], smx[16];
    __shared__ float fmn, fmx;
    int w = threadIdx.x >> 6, lane = threadIdx.x & 63;
    if (lane == 0) { smn[w] = mn; smx[w] = mx; }
    __syncthreads();
    if (threadIdx.x == 0) {
        float a = INFINITY, c = -INFINITY;
        for (int i = 0; i < 16; ++i) {
            a = fminf(a, smn[i]);
            c = fmaxf(c, smx[i]);
        }
        fmn = a; fmx = c;
    }
    __syncthreads();
    float mnv = fmn;
    float inv = 1.0f / (fmx - mnv + EPS);
    for (int e = threadIdx.x; e < E; e += 1024) {
        out[(size_t)b * E + e] = W[e] * (1.0f + LAM * (row[e] - mnv) * inv);
    }
}

extern "C" void kernel_launch(void* const* d_in, const int* in_sizes, int n_in,
                              void* d_out, int out_size, void* d_ws, size_t ws_size,
                              hipStream_t stream) {
    const float* x_raw    = (const float*)d_in[0];
    const float* W        = (const float*)d_in[1];
    const int*   members  = (const int*)d_in[2];
    const int*   centers  = (const int*)d_in[3];
    const int*   edge_ids = (const int*)d_in[4]; (void)edge_ids;
    const float* counts   = (const float*)d_in[5];
    float* out = (float*)d_out;

    _Float16* ufeat   = (_Float16*)d_ws;                    // 2*N*256 halves = 5.12 MB
    float* mean_sim   = (float*)(ufeat + 2 * HN);           // B*E floats = 640 KB
    int*   starts     = (int*)(mean_sim + (size_t)B * E);   // E ints

    feat_scan_kernel<<<626, 256, 0, stream>>>(x_raw, counts, ufeat, starts);
    // 2512 = 314 groups of 8 blocks (4 x h=0, 4 x h=1); e4 padded, checked in-kernel
    sim_kernel<<<2512, 256, 0, stream>>>(ufeat, members, centers, starts,
                                         counts, mean_sim);
    norm_kernel<<<B, 1024, 0, stream>>>(mean_sim, W, out);
}